// Round 12
// baseline (639.527 us; speedup 1.0000x reference)
//
#include <hip/hip_runtime.h>
#include <stdint.h>
#include <math.h>

// ---------------------------------------------------------------------------
// ROUND 12: FULL PIPELINE, COMPILE-COST-CAPPED (unpoisoned).
// Root cause of rounds 1-7/9/10 "timeouts" identified in R11: hipcc compile
// blowup on TUs where the ~100-op threefry body is inlined into 64-iteration
// loops (R8: 1 call, pytest 2.8s; R11: 64-call loop, pytest 413s; full
// pipeline with 2 loops + inlined Cephes: >600s). Execution arithmetic rules
// out runtime (0.2ms). FIX: __noinline__ on threefry / xla_logf / xla_expf /
// gumbel_at — each compiled once, loop bodies stay ~20 instrs + calls.
// Numerics stack (H1-H6) unchanged; hardening (clamped gathers, no
// workspace, dual-width ints, uniform barriers) unchanged.
// ---------------------------------------------------------------------------

__device__ __forceinline__ uint32_t rotl32(uint32_t x, int d) {
  return (x << d) | (x >> (32 - d));
}

// JAX threefry2x32 (20 rounds), bit-exact per jax/_src/prng.py.
// __noinline__ is THE fix: exactly one ~100-instr copy in the code object.
__device__ __attribute__((noinline)) void threefry2x32(
    uint32_t k0, uint32_t k1, uint32_t c0, uint32_t c1,
    uint32_t& o0, uint32_t& o1) {
  const uint32_t ks2 = k0 ^ k1 ^ 0x1BD11BDAu;
  uint32_t x0 = c0 + k0;
  uint32_t x1 = c1 + k1;
  x0 += x1; x1 = rotl32(x1, 13); x1 ^= x0;
  x0 += x1; x1 = rotl32(x1, 15); x1 ^= x0;
  x0 += x1; x1 = rotl32(x1, 26); x1 ^= x0;
  x0 += x1; x1 = rotl32(x1, 6);  x1 ^= x0;
  x0 += k1;  x1 += ks2 + 1u;
  x0 += x1; x1 = rotl32(x1, 17); x1 ^= x0;
  x0 += x1; x1 = rotl32(x1, 29); x1 ^= x0;
  x0 += x1; x1 = rotl32(x1, 16); x1 ^= x0;
  x0 += x1; x1 = rotl32(x1, 24); x1 ^= x0;
  x0 += ks2; x1 += k0 + 2u;
  x0 += x1; x1 = rotl32(x1, 13); x1 ^= x0;
  x0 += x1; x1 = rotl32(x1, 15); x1 ^= x0;
  x0 += x1; x1 = rotl32(x1, 26); x1 ^= x0;
  x0 += x1; x1 = rotl32(x1, 6);  x1 ^= x0;
  x0 += k0;  x1 += k1 + 3u;
  x0 += x1; x1 = rotl32(x1, 17); x1 ^= x0;
  x0 += x1; x1 = rotl32(x1, 29); x1 ^= x0;
  x0 += x1; x1 = rotl32(x1, 16); x1 ^= x0;
  x0 += x1; x1 = rotl32(x1, 24); x1 ^= x0;
  x0 += k1;  x1 += ks2 + 4u;
  x0 += x1; x1 = rotl32(x1, 13); x1 ^= x0;
  x0 += x1; x1 = rotl32(x1, 15); x1 ^= x0;
  x0 += x1; x1 = rotl32(x1, 26); x1 ^= x0;
  x0 += x1; x1 = rotl32(x1, 6);  x1 ^= x0;
  x0 += ks2; x1 += k0 + 5u;
  o0 = x0; o1 = x1;
}

// Host copy for key derivation (host compile is cheap; inline is fine there).
static void threefry2x32_host(uint32_t k0, uint32_t k1, uint32_t c0, uint32_t c1,
                              uint32_t& o0, uint32_t& o1) {
  auto rot = [](uint32_t x, int d) { return (x << d) | (x >> (32 - d)); };
  const uint32_t ks2 = k0 ^ k1 ^ 0x1BD11BDAu;
  uint32_t x0 = c0 + k0;
  uint32_t x1 = c1 + k1;
  x0 += x1; x1 = rot(x1, 13); x1 ^= x0;
  x0 += x1; x1 = rot(x1, 15); x1 ^= x0;
  x0 += x1; x1 = rot(x1, 26); x1 ^= x0;
  x0 += x1; x1 = rot(x1, 6);  x1 ^= x0;
  x0 += k1;  x1 += ks2 + 1u;
  x0 += x1; x1 = rot(x1, 17); x1 ^= x0;
  x0 += x1; x1 = rot(x1, 29); x1 ^= x0;
  x0 += x1; x1 = rot(x1, 16); x1 ^= x0;
  x0 += x1; x1 = rot(x1, 24); x1 ^= x0;
  x0 += ks2; x1 += k0 + 2u;
  x0 += x1; x1 = rot(x1, 13); x1 ^= x0;
  x0 += x1; x1 = rot(x1, 15); x1 ^= x0;
  x0 += x1; x1 = rot(x1, 26); x1 ^= x0;
  x0 += x1; x1 = rot(x1, 6);  x1 ^= x0;
  x0 += k0;  x1 += k1 + 3u;
  x0 += x1; x1 = rot(x1, 17); x1 ^= x0;
  x0 += x1; x1 = rot(x1, 29); x1 ^= x0;
  x0 += x1; x1 = rot(x1, 16); x1 ^= x0;
  x0 += x1; x1 = rot(x1, 24); x1 ^= x0;
  x0 += k1;  x1 += ks2 + 4u;
  x0 += x1; x1 = rot(x1, 13); x1 ^= x0;
  x0 += x1; x1 = rot(x1, 15); x1 ^= x0;
  x0 += x1; x1 = rot(x1, 26); x1 ^= x0;
  x0 += x1; x1 = rot(x1, 6);  x1 ^= x0;
  x0 += ks2; x1 += k0 + 5u;
  o0 = x0; o1 = x1;
}

// XLA-CPU f32 log: Cephes plog (H3). Explicit _rn ops where contraction
// would change bits. Compiled once (__noinline__).
__device__ __attribute__((noinline)) float xla_logf(float x) {
  uint32_t ix = __float_as_uint(x);
  float e = (float)((int)(ix >> 23) - 126);
  float m = __uint_as_float((ix & 0x807fffffu) | 0x3f000000u);  // [0.5, 1)
  if (m < 0.707106781186547524f) { e -= 1.0f; m = __fadd_rn(m, m); }
  m = __fsub_rn(m, 1.0f);
  float x2 = __fmul_rn(m, m);
  float x3 = __fmul_rn(x2, m);
  float y  = fmaf(7.0376836292e-2f,  m, -1.1514610310e-1f);
  float y1 = fmaf(-1.2420140846e-1f, m,  1.4249322787e-1f);
  float y2 = fmaf(2.0000714765e-1f,  m, -2.4999993993e-1f);
  y  = fmaf(y,  m,  1.1676998740e-1f);
  y1 = fmaf(y1, m, -1.6668057665e-1f);
  y2 = fmaf(y2, m,  3.3333331174e-1f);
  y = fmaf(y, x3, y1);
  y = fmaf(y, x3, y2);
  y = __fmul_rn(y, x3);
  y = fmaf(e, -2.12194440e-4f, y);
  y = __fsub_rn(y, __fmul_rn(0.5f, x2));
  float r = __fadd_rn(m, y);
  r = fmaf(e, 0.693359375f, r);
  return r;
}

// XLA-CPU f32 exp: classic Cephes pexp (H4). Inputs in [-46, 0].
__device__ __attribute__((noinline)) float xla_expf(float x) {
  float fx = floorf(fmaf(x, 1.44269504088896341f, 0.5f));
  float r = __fsub_rn(x, __fmul_rn(fx, 0.693359375f));
  r = __fsub_rn(r, __fmul_rn(fx, -2.12194440e-4f));
  float zz = __fmul_rn(r, r);
  float y = 1.9875691500e-4f;
  y = fmaf(y, r, 1.3981999507e-3f);
  y = fmaf(y, r, 8.3334519073e-3f);
  y = fmaf(y, r, 4.1665795894e-2f);
  y = fmaf(y, r, 1.6666665459e-1f);
  y = fmaf(y, r, 5.0000001201e-1f);
  y = fmaf(y, zz, r);
  y = __fadd_rn(y, 1.0f);
  int n = (int)fx;
  float s = __uint_as_float((uint32_t)(n + 127) << 23);
  return __fmul_rn(y, s);
}

// XLA-CPU row reduction, width 8 + tree (H6). Small; inline is safe.
__device__ __forceinline__ float xla_rowsum64(const float* v) {
  float acc[8];
  #pragma unroll
  for (int l = 0; l < 8; ++l) acc[l] = v[l];
  #pragma unroll
  for (int t = 1; t < 8; ++t) {
    #pragma unroll
    for (int l = 0; l < 8; ++l) acc[l] = __fadd_rn(acc[l], v[t * 8 + l]);
  }
  float b0 = __fadd_rn(acc[0], acc[4]);
  float b1 = __fadd_rn(acc[1], acc[5]);
  float b2 = __fadd_rn(acc[2], acc[6]);
  float b3 = __fadd_rn(acc[3], acc[7]);
  return __fadd_rn(__fadd_rn(b0, b2), __fadd_rn(b1, b3));
}

// Gumbel at flat counter m (H1/H2): bits = x0^x1, uniform(minval=tiny),
// g = -log(-log(u)). Compiled once (__noinline__).
__device__ __attribute__((noinline)) float gumbel_at(uint32_t k0, uint32_t k1,
                                                     uint32_t m) {
  uint32_t o0, o1;
  threefry2x32(k0, k1, 0u, m, o0, o1);
  uint32_t bits = o0 ^ o1;                                       // KNOB H2
  float f = __fsub_rn(__uint_as_float((bits >> 9) | 0x3f800000u), 1.0f);
  float u = (f == 0.0f) ? 1.17549435082228751e-38f : f;          // minval=tiny
  return -xla_logf(-xla_logf(u));
}

__device__ __forceinline__ int clampi(int v, int lo, int hi) {
  return v < lo ? lo : (v > hi ? hi : v);
}

// Dual-width integer load (int64 vs int32 materialization).
__device__ __forceinline__ int ld_int(const int* p32, int i, bool is64) {
  return p32[is64 ? 2 * i : i];
}

// ---------------------------------------------------------------------------
// Fused kernel: one 256-thread block per batch row. No workspace, clamped
// gathers, uniform barriers. Phase 1: r0/r1 rows (H5 serial-k fmaf),
// softmaxes, l0 = log((r1s@wkk^T)*r0s). Phase 2: categorical(ka),
// categorical(kb), uniform(kc), bucket lookup.
// ---------------------------------------------------------------------------
__global__ void __launch_bounds__(256) k_fused(
    const float* __restrict__ query, const float* __restrict__ c0g,
    const float* __restrict__ c1g, const float* __restrict__ wkk,
    const int* __restrict__ indptr, const int* __restrict__ indices,
    float* __restrict__ out_items, float* __restrict__ out_prob,
    int nneg, int n_items,
    uint32_t ka0, uint32_t ka1, uint32_t kb0, uint32_t kb1,
    uint32_t kc0, uint32_t kc1) {
  const int b = blockIdx.x;
  const int t = threadIdx.x;
  const bool is64 = (indptr[1] == 0);   // int64-materialization detection

  __shared__ float sq0[64], sq1[64], sa[64];
  __shared__ float sr0[64], sr1[64], sr1s[64], sl0[64];

  if (t < 64) {
    sq0[t] = query[b * 128 + t];
    sq1[t] = query[b * 128 + 64 + t];
  }
  __syncthreads();

  float acc0 = 0.0f, acc1 = 0.0f;
  if (t < 64) {
    const float* c0r = c0g + t * 64;
    const float* c1r = c1g + t * 64;
    for (int k = 0; k < 64; ++k) {
      acc0 = fmaf(sq0[k], c0r[k], acc0);   // Eigen gebp serial-k (H5)
      acc1 = fmaf(sq1[k], c1r[k], acc1);
    }
    sr0[t] = acc0;
    sr1[t] = acc1;
    sa[t] = acc0;
  }
  __syncthreads();

  float e0 = 0.0f;
  if (t < 64) {
    float mx = sa[0];
    for (int k = 1; k < 64; ++k) mx = fmaxf(mx, sa[k]);
    e0 = xla_expf(__fsub_rn(acc0, mx));
  }
  __syncthreads();
  if (t < 64) sa[t] = e0;
  __syncthreads();

  float r0s = 0.0f;
  if (t < 64) {
    float s = xla_rowsum64(sa);
    r0s = e0 / s;
  }
  __syncthreads();
  if (t < 64) sa[t] = acc1;
  __syncthreads();

  float e1 = 0.0f;
  if (t < 64) {
    float mx = sa[0];
    for (int k = 1; k < 64; ++k) mx = fmaxf(mx, sa[k]);
    e1 = xla_expf(__fsub_rn(acc1, mx));
  }
  __syncthreads();
  if (t < 64) sa[t] = e1;
  __syncthreads();

  if (t < 64) {
    float s1 = xla_rowsum64(sa);
    sr1s[t] = e1 / s1;
  }
  __syncthreads();

  if (t < 64) {
    float d = 0.0f;
    const float* wr = wkk + t * 64;
    for (int k = 0; k < 64; ++k) d = fmaf(sr1s[k], wr[k], d);
    sl0[t] = xla_logf(__fmul_rn(d, r0s));
  }
  __syncthreads();

  for (int j = t; j < nneg; j += blockDim.x) {
    int tid = b * nneg + j;
    uint32_t mbase = (uint32_t)tid * 64u;

    // k0 = argmax_k gumbel_a + log(s0); first-max-wins
    float best = -INFINITY; int k0 = 0;
    #pragma unroll 1
    for (int k = 0; k < 64; ++k) {
      float g = gumbel_at(ka0, ka1, mbase + (uint32_t)k);
      float v = __fadd_rn(g, sl0[k]);
      if (v > best) { best = v; k0 = k; }
    }

    // k1 = argmax_k gumbel_b + log(wkk[k0,k] * r1s[b,k])
    const float* wr = wkk + k0 * 64;
    float best1 = -INFINITY; int k1 = 0;
    #pragma unroll 1
    for (int k = 0; k < 64; ++k) {
      float g = gumbel_at(kb0, kb1, mbase + (uint32_t)k);
      float s1v = __fmul_rn(wr[k], sr1s[k]);
      float v = __fadd_rn(g, xla_logf(s1v));
      if (v > best1) { best1 = v; k1 = k; }
    }

    float p01 = __fadd_rn(sr0[k0], sr1[k1]);

    // uniform within bucket (key kc)
    uint32_t o0, o1;
    threefry2x32(kc0, kc1, 0u, (uint32_t)tid, o0, o1);
    uint32_t bits = o0 ^ o1;                                    // KNOB H2
    float u = __fsub_rn(__uint_as_float((bits >> 9) | 0x3f800000u), 1.0f);

    int k01 = clampi(k0 * 64 + k1, 0, 4095);
    int st  = ld_int(indptr, k01, is64);
    int en  = ld_int(indptr, k01 + 1, is64);
    int cnt = en - st;
    int idx = (int)floorf(__fmul_rn((float)cnt, u));
    int cap = cnt - 1; if (cap < 0) cap = 0;
    if (idx > cap) idx = cap;
    if (idx < 0) idx = 0;
    int gidx = clampi(st + idx, 0, n_items - 1);      // fault-proof gather
    out_items[tid] = (float)(ld_int(indices, gidx, is64) + 1);  // exact in f32
    out_prob[tid] = p01;
  }
}

// ---------------------------------------------------------------------------
// pos_prop[b] = sum(c0_[cd0[pos]] * q0) + sum(c1_[cd1[pos]] * q1)
// ---------------------------------------------------------------------------
__global__ void __launch_bounds__(256) k_pos(
    const float* __restrict__ query, const int* __restrict__ pos_items,
    const int* __restrict__ cd0, const int* __restrict__ cd1,
    const float* __restrict__ c0_, const float* __restrict__ c1_,
    float* __restrict__ out, int B, int cd_len) {
  int b = blockIdx.x * blockDim.x + threadIdx.x;
  if (b >= B) return;
  const bool is64p = (pos_items[1] == 0);
  const bool is64c = (cd0[1] == 0);
  int it = clampi(ld_int(pos_items, b, is64p), 0, cd_len - 1);
  int kp0 = clampi(ld_int(cd0, it, is64c), 0, 64);
  int kp1 = clampi(ld_int(cd1, it, is64c), 0, 64);
  const float* q = query + b * 128;
  const float* a0 = c0_ + kp0 * 64;
  const float* a1 = c1_ + kp1 * 64;

  float acc[8];
  #pragma unroll
  for (int l = 0; l < 8; ++l) acc[l] = __fmul_rn(a0[l], q[l]);
  #pragma unroll
  for (int t2 = 1; t2 < 8; ++t2) {
    #pragma unroll
    for (int l = 0; l < 8; ++l)
      acc[l] = __fadd_rn(acc[l], __fmul_rn(a0[t2 * 8 + l], q[t2 * 8 + l]));
  }
  float s0 = __fadd_rn(__fadd_rn(__fadd_rn(acc[0], acc[4]), __fadd_rn(acc[2], acc[6])),
                       __fadd_rn(__fadd_rn(acc[1], acc[5]), __fadd_rn(acc[3], acc[7])));

  #pragma unroll
  for (int l = 0; l < 8; ++l) acc[l] = __fmul_rn(a1[l], q[64 + l]);
  #pragma unroll
  for (int t2 = 1; t2 < 8; ++t2) {
    #pragma unroll
    for (int l = 0; l < 8; ++l)
      acc[l] = __fadd_rn(acc[l], __fmul_rn(a1[t2 * 8 + l], q[64 + t2 * 8 + l]));
  }
  float s1 = __fadd_rn(__fadd_rn(__fadd_rn(acc[0], acc[4]), __fadd_rn(acc[2], acc[6])),
                       __fadd_rn(__fadd_rn(acc[1], acc[5]), __fadd_rn(acc[3], acc[7])));
  out[b] = __fadd_rn(s0, s1);
}

// ---------------------------------------------------------------------------
// Launch — no workspace, launches only, capture-safe.
// ---------------------------------------------------------------------------
extern "C" void kernel_launch(void* const* d_in, const int* in_sizes, int n_in,
                              void* d_out, int out_size, void* d_ws, size_t ws_size,
                              hipStream_t stream) {
  const float* query     = (const float*)d_in[0];
  const int*   pos_items = (const int*)d_in[1];
  const float* c0  = (const float*)d_in[3];
  const float* c1  = (const float*)d_in[4];
  const float* wkk = (const float*)d_in[5];
  const float* c0_ = (const float*)d_in[6];
  const float* c1_ = (const float*)d_in[7];
  const int* cd0     = (const int*)d_in[8];
  const int* cd1     = (const int*)d_in[9];
  const int* indices = (const int*)d_in[10];
  const int* indptr  = (const int*)d_in[11];

  const int B = in_sizes[0] / 128;            // 4096
  int nneg = (out_size - B) / (2 * B);        // 200
  if (nneg < 1) nneg = 1;
  const int total = B * nneg;
  const int n_items = in_sizes[10];           // 1,000,000
  const int cd_len  = in_sizes[8];            // 1,000,001

  float* out = (float*)d_out;
  float* out_pos   = out;               // [B]
  float* out_items = out + B;           // [B*nneg]
  float* out_prob  = out + B + total;   // [B*nneg]

  // split(key(42), 3), partitionable foldlike (H1): child i = TF(key,(0,i))
  uint32_t ka0, ka1, kb0, kb1, kc0, kc1;
  threefry2x32_host(0u, 42u, 0u, 0u, ka0, ka1);
  threefry2x32_host(0u, 42u, 0u, 1u, kb0, kb1);
  threefry2x32_host(0u, 42u, 0u, 2u, kc0, kc1);

  k_fused<<<B, 256, 0, stream>>>(query, c0, c1, wkk, indptr, indices,
                                 out_items, out_prob, nneg, n_items,
                                 ka0, ka1, kb0, kb1, kc0, kc1);
  k_pos<<<(B + 255) / 256, 256, 0, stream>>>(query, pos_items, cd0, cd1,
                                             c0_, c1_, out_pos, B, cd_len);
}

// Round 13
// 443.307 us; speedup vs baseline: 1.4426x; 1.4426x over previous
//
#include <hip/hip_runtime.h>
#include <stdint.h>
#include <math.h>

// ---------------------------------------------------------------------------
// ROUND 13: OP-COUNT REDUCTION (baseline R12: 640us, VALUBusy 94%, bit-exact).
// R12 post-mortem: ~62k ops/sample measured vs ~24k useful => call-ABI
// overhead from NESTED noinline calls (gumbel_at -> threefry + 2x logf = 4
// calls/gumbel) + loop-2 recomputing log(wkk[k0,k]*r1s[k]) per sample.
// Fix 1: gumbel_at becomes ONE self-contained noinline function (threefry and
//   both Cephes logs inlined INSIDE it as straight-line code — compiled once,
//   never inlined into a loop, so the R1-R11 compile blowup stays defused).
// Fix 2: per-block LDS table lw[kk][k] = log(wkk[kk,k]*r1s[b,k]) (stride 65,
//   bank-conflict-free), 4096 logf/block amortized over 200 samples replaces
//   64 logf/sample in loop 2. Same inputs, same function => identical bits.
// Numerics stack (H1-H6, verified bit-exact in R12) untouched.
// ---------------------------------------------------------------------------

__device__ __host__ __forceinline__ uint32_t rotl32(uint32_t x, int d) {
  return (x << d) | (x >> (32 - d));
}

// 20-round threefry2x32 core (bit-exact per jax/_src/prng.py). __forceinline__
// but ONLY ever called from straight-line noinline wrappers — never loops.
__device__ __forceinline__ void tf_core(uint32_t k0, uint32_t k1,
                                        uint32_t c0, uint32_t c1,
                                        uint32_t& o0, uint32_t& o1) {
  const uint32_t ks2 = k0 ^ k1 ^ 0x1BD11BDAu;
  uint32_t x0 = c0 + k0;
  uint32_t x1 = c1 + k1;
  x0 += x1; x1 = rotl32(x1, 13); x1 ^= x0;
  x0 += x1; x1 = rotl32(x1, 15); x1 ^= x0;
  x0 += x1; x1 = rotl32(x1, 26); x1 ^= x0;
  x0 += x1; x1 = rotl32(x1, 6);  x1 ^= x0;
  x0 += k1;  x1 += ks2 + 1u;
  x0 += x1; x1 = rotl32(x1, 17); x1 ^= x0;
  x0 += x1; x1 = rotl32(x1, 29); x1 ^= x0;
  x0 += x1; x1 = rotl32(x1, 16); x1 ^= x0;
  x0 += x1; x1 = rotl32(x1, 24); x1 ^= x0;
  x0 += ks2; x1 += k0 + 2u;
  x0 += x1; x1 = rotl32(x1, 13); x1 ^= x0;
  x0 += x1; x1 = rotl32(x1, 15); x1 ^= x0;
  x0 += x1; x1 = rotl32(x1, 26); x1 ^= x0;
  x0 += x1; x1 = rotl32(x1, 6);  x1 ^= x0;
  x0 += k0;  x1 += k1 + 3u;
  x0 += x1; x1 = rotl32(x1, 17); x1 ^= x0;
  x0 += x1; x1 = rotl32(x1, 29); x1 ^= x0;
  x0 += x1; x1 = rotl32(x1, 16); x1 ^= x0;
  x0 += x1; x1 = rotl32(x1, 24); x1 ^= x0;
  x0 += k1;  x1 += ks2 + 4u;
  x0 += x1; x1 = rotl32(x1, 13); x1 ^= x0;
  x0 += x1; x1 = rotl32(x1, 15); x1 ^= x0;
  x0 += x1; x1 = rotl32(x1, 26); x1 ^= x0;
  x0 += x1; x1 = rotl32(x1, 6);  x1 ^= x0;
  x0 += ks2; x1 += k0 + 5u;
  o0 = x0; o1 = x1;
}

// Cephes plog core (H3). Same constraint: straight-line call sites only.
__device__ __forceinline__ float logf_core(float x) {
  uint32_t ix = __float_as_uint(x);
  float e = (float)((int)(ix >> 23) - 126);
  float m = __uint_as_float((ix & 0x807fffffu) | 0x3f000000u);  // [0.5, 1)
  if (m < 0.707106781186547524f) { e -= 1.0f; m = __fadd_rn(m, m); }
  m = __fsub_rn(m, 1.0f);
  float x2 = __fmul_rn(m, m);
  float x3 = __fmul_rn(x2, m);
  float y  = fmaf(7.0376836292e-2f,  m, -1.1514610310e-1f);
  float y1 = fmaf(-1.2420140846e-1f, m,  1.4249322787e-1f);
  float y2 = fmaf(2.0000714765e-1f,  m, -2.4999993993e-1f);
  y  = fmaf(y,  m,  1.1676998740e-1f);
  y1 = fmaf(y1, m, -1.6668057665e-1f);
  y2 = fmaf(y2, m,  3.3333331174e-1f);
  y = fmaf(y, x3, y1);
  y = fmaf(y, x3, y2);
  y = __fmul_rn(y, x3);
  y = fmaf(e, -2.12194440e-4f, y);
  y = __fsub_rn(y, __fmul_rn(0.5f, x2));
  float r = __fadd_rn(m, y);
  r = fmaf(e, 0.693359375f, r);
  return r;
}

// Noinline wrappers: compiled once each; these are what loops may call.
__device__ __attribute__((noinline)) void threefry2x32(
    uint32_t k0, uint32_t k1, uint32_t c0, uint32_t c1,
    uint32_t& o0, uint32_t& o1) {
  tf_core(k0, k1, c0, c1, o0, o1);
}

__device__ __attribute__((noinline)) float xla_logf(float x) {
  return logf_core(x);
}

// Cephes pexp (H4), inputs in [-46, 0]. Phase-1 only.
__device__ __attribute__((noinline)) float xla_expf(float x) {
  float fx = floorf(fmaf(x, 1.44269504088896341f, 0.5f));
  float r = __fsub_rn(x, __fmul_rn(fx, 0.693359375f));
  r = __fsub_rn(r, __fmul_rn(fx, -2.12194440e-4f));
  float zz = __fmul_rn(r, r);
  float y = 1.9875691500e-4f;
  y = fmaf(y, r, 1.3981999507e-3f);
  y = fmaf(y, r, 8.3334519073e-3f);
  y = fmaf(y, r, 4.1665795894e-2f);
  y = fmaf(y, r, 1.6666665459e-1f);
  y = fmaf(y, r, 5.0000001201e-1f);
  y = fmaf(y, zz, r);
  y = __fadd_rn(y, 1.0f);
  int n = (int)fx;
  float s = __uint_as_float((uint32_t)(n + 127) << 23);
  return __fmul_rn(y, s);
}

// SELF-CONTAINED gumbel (fix 1): threefry + both Cephes logs inlined inside
// ONE noinline function. 1 call per gumbel instead of 4 nested calls.
// Bit-identical op sequence to R12's gumbel_at.
__device__ __attribute__((noinline)) float gumbel_at(uint32_t k0, uint32_t k1,
                                                     uint32_t m) {
  uint32_t o0, o1;
  tf_core(k0, k1, 0u, m, o0, o1);
  uint32_t bits = o0 ^ o1;                                       // H2
  float f = __fsub_rn(__uint_as_float((bits >> 9) | 0x3f800000u), 1.0f);
  float u = (f == 0.0f) ? 1.17549435082228751e-38f : f;          // minval=tiny
  return -logf_core(-logf_core(u));
}

// XLA-CPU row reduction, width 8 + tree (H6).
__device__ __forceinline__ float xla_rowsum64(const float* v) {
  float acc[8];
  #pragma unroll
  for (int l = 0; l < 8; ++l) acc[l] = v[l];
  #pragma unroll
  for (int t = 1; t < 8; ++t) {
    #pragma unroll
    for (int l = 0; l < 8; ++l) acc[l] = __fadd_rn(acc[l], v[t * 8 + l]);
  }
  float b0 = __fadd_rn(acc[0], acc[4]);
  float b1 = __fadd_rn(acc[1], acc[5]);
  float b2 = __fadd_rn(acc[2], acc[6]);
  float b3 = __fadd_rn(acc[3], acc[7]);
  return __fadd_rn(__fadd_rn(b0, b2), __fadd_rn(b1, b3));
}

__device__ __forceinline__ int clampi(int v, int lo, int hi) {
  return v < lo ? lo : (v > hi ? hi : v);
}

__device__ __forceinline__ int ld_int(const int* p32, int i, bool is64) {
  return p32[is64 ? 2 * i : i];
}

static void threefry2x32_host(uint32_t k0, uint32_t k1, uint32_t c0, uint32_t c1,
                              uint32_t& o0, uint32_t& o1) {
  const uint32_t ks2 = k0 ^ k1 ^ 0x1BD11BDAu;
  uint32_t x0 = c0 + k0;
  uint32_t x1 = c1 + k1;
  x0 += x1; x1 = rotl32(x1, 13); x1 ^= x0;
  x0 += x1; x1 = rotl32(x1, 15); x1 ^= x0;
  x0 += x1; x1 = rotl32(x1, 26); x1 ^= x0;
  x0 += x1; x1 = rotl32(x1, 6);  x1 ^= x0;
  x0 += k1;  x1 += ks2 + 1u;
  x0 += x1; x1 = rotl32(x1, 17); x1 ^= x0;
  x0 += x1; x1 = rotl32(x1, 29); x1 ^= x0;
  x0 += x1; x1 = rotl32(x1, 16); x1 ^= x0;
  x0 += x1; x1 = rotl32(x1, 24); x1 ^= x0;
  x0 += ks2; x1 += k0 + 2u;
  x0 += x1; x1 = rotl32(x1, 13); x1 ^= x0;
  x0 += x1; x1 = rotl32(x1, 15); x1 ^= x0;
  x0 += x1; x1 = rotl32(x1, 26); x1 ^= x0;
  x0 += x1; x1 = rotl32(x1, 6);  x1 ^= x0;
  x0 += k0;  x1 += k1 + 3u;
  x0 += x1; x1 = rotl32(x1, 17); x1 ^= x0;
  x0 += x1; x1 = rotl32(x1, 29); x1 ^= x0;
  x0 += x1; x1 = rotl32(x1, 16); x1 ^= x0;
  x0 += x1; x1 = rotl32(x1, 24); x1 ^= x0;
  x0 += k1;  x1 += ks2 + 4u;
  x0 += x1; x1 = rotl32(x1, 13); x1 ^= x0;
  x0 += x1; x1 = rotl32(x1, 15); x1 ^= x0;
  x0 += x1; x1 = rotl32(x1, 26); x1 ^= x0;
  x0 += x1; x1 = rotl32(x1, 6);  x1 ^= x0;
  x0 += ks2; x1 += k0 + 5u;
  o0 = x0; o1 = x1;
}

// ---------------------------------------------------------------------------
// Fused kernel. Phase 1 (t<64): r0/r1 rows, softmaxes, sl0. Table phase
// (all 256 threads): lw[kk][k] = log(wkk[kk,k]*r1s[k]), stride 65. Phase 2:
// one sample per thread.
// ---------------------------------------------------------------------------
__global__ void __launch_bounds__(256) k_fused(
    const float* __restrict__ query, const float* __restrict__ c0g,
    const float* __restrict__ c1g, const float* __restrict__ wkk,
    const int* __restrict__ indptr, const int* __restrict__ indices,
    float* __restrict__ out_items, float* __restrict__ out_prob,
    int nneg, int n_items,
    uint32_t ka0, uint32_t ka1, uint32_t kb0, uint32_t kb1,
    uint32_t kc0, uint32_t kc1) {
  const int b = blockIdx.x;
  const int t = threadIdx.x;
  const bool is64 = (indptr[1] == 0);   // int64-materialization detection

  __shared__ float sq0[64], sq1[64], sa[64];
  __shared__ float sr0[64], sr1[64], sr1s[64], sl0[64];
  __shared__ float lw[64 * 65];         // stride 65: bank-conflict-free

  if (t < 64) {
    sq0[t] = query[b * 128 + t];
    sq1[t] = query[b * 128 + 64 + t];
  }
  __syncthreads();

  float acc0 = 0.0f, acc1 = 0.0f;
  if (t < 64) {
    const float* c0r = c0g + t * 64;
    const float* c1r = c1g + t * 64;
    for (int k = 0; k < 64; ++k) {
      acc0 = fmaf(sq0[k], c0r[k], acc0);   // Eigen gebp serial-k (H5)
      acc1 = fmaf(sq1[k], c1r[k], acc1);
    }
    sr0[t] = acc0;
    sr1[t] = acc1;
    sa[t] = acc0;
  }
  __syncthreads();

  float e0 = 0.0f;
  if (t < 64) {
    float mx = sa[0];
    for (int k = 1; k < 64; ++k) mx = fmaxf(mx, sa[k]);
    e0 = xla_expf(__fsub_rn(acc0, mx));
  }
  __syncthreads();
  if (t < 64) sa[t] = e0;
  __syncthreads();

  float r0s = 0.0f;
  if (t < 64) {
    float s = xla_rowsum64(sa);
    r0s = e0 / s;
  }
  __syncthreads();
  if (t < 64) sa[t] = acc1;
  __syncthreads();

  float e1 = 0.0f;
  if (t < 64) {
    float mx = sa[0];
    for (int k = 1; k < 64; ++k) mx = fmaxf(mx, sa[k]);
    e1 = xla_expf(__fsub_rn(acc1, mx));
  }
  __syncthreads();
  if (t < 64) sa[t] = e1;
  __syncthreads();

  if (t < 64) {
    float s1 = xla_rowsum64(sa);
    sr1s[t] = e1 / s1;
  }
  __syncthreads();

  // lw table: 4096 entries, 16 per thread (amortized over nneg samples).
  for (int i = t; i < 4096; i += 256) {
    int kk = i >> 6, k = i & 63;
    lw[kk * 65 + k] = xla_logf(__fmul_rn(wkk[i], sr1s[k]));
  }
  if (t < 64) {
    float d = 0.0f;
    const float* wr = wkk + t * 64;
    for (int k = 0; k < 64; ++k) d = fmaf(sr1s[k], wr[k], d);
    sl0[t] = xla_logf(__fmul_rn(d, r0s));
  }
  __syncthreads();

  for (int j = t; j < nneg; j += blockDim.x) {
    int tid = b * nneg + j;
    uint32_t mbase = (uint32_t)tid * 64u;

    // k0 = argmax_k gumbel_a + log(s0); first-max-wins
    float best = -INFINITY; int k0 = 0;
    #pragma unroll 1
    for (int k = 0; k < 64; ++k) {
      float g = gumbel_at(ka0, ka1, mbase + (uint32_t)k);
      float v = __fadd_rn(g, sl0[k]);
      if (v > best) { best = v; k0 = k; }
    }

    // k1 = argmax_k gumbel_b + lw[k0][k]  (precomputed log, identical bits)
    const float* lwr = lw + k0 * 65;
    float best1 = -INFINITY; int k1 = 0;
    #pragma unroll 1
    for (int k = 0; k < 64; ++k) {
      float g = gumbel_at(kb0, kb1, mbase + (uint32_t)k);
      float v = __fadd_rn(g, lwr[k]);
      if (v > best1) { best1 = v; k1 = k; }
    }

    float p01 = __fadd_rn(sr0[k0], sr1[k1]);

    // uniform within bucket (key kc)
    uint32_t o0, o1;
    threefry2x32(kc0, kc1, 0u, (uint32_t)tid, o0, o1);
    uint32_t bits = o0 ^ o1;                                    // H2
    float u = __fsub_rn(__uint_as_float((bits >> 9) | 0x3f800000u), 1.0f);

    int k01 = clampi(k0 * 64 + k1, 0, 4095);
    int st  = ld_int(indptr, k01, is64);
    int en  = ld_int(indptr, k01 + 1, is64);
    int cnt = en - st;
    int idx = (int)floorf(__fmul_rn((float)cnt, u));
    int cap = cnt - 1; if (cap < 0) cap = 0;
    if (idx > cap) idx = cap;
    if (idx < 0) idx = 0;
    int gidx = clampi(st + idx, 0, n_items - 1);      // fault-proof gather
    out_items[tid] = (float)(ld_int(indices, gidx, is64) + 1);  // exact in f32
    out_prob[tid] = p01;
  }
}

// ---------------------------------------------------------------------------
// pos_prop[b] = sum(c0_[cd0[pos]] * q0) + sum(c1_[cd1[pos]] * q1)
// ---------------------------------------------------------------------------
__global__ void __launch_bounds__(256) k_pos(
    const float* __restrict__ query, const int* __restrict__ pos_items,
    const int* __restrict__ cd0, const int* __restrict__ cd1,
    const float* __restrict__ c0_, const float* __restrict__ c1_,
    float* __restrict__ out, int B, int cd_len) {
  int b = blockIdx.x * blockDim.x + threadIdx.x;
  if (b >= B) return;
  const bool is64p = (pos_items[1] == 0);
  const bool is64c = (cd0[1] == 0);
  int it = clampi(ld_int(pos_items, b, is64p), 0, cd_len - 1);
  int kp0 = clampi(ld_int(cd0, it, is64c), 0, 64);
  int kp1 = clampi(ld_int(cd1, it, is64c), 0, 64);
  const float* q = query + b * 128;
  const float* a0 = c0_ + kp0 * 64;
  const float* a1 = c1_ + kp1 * 64;

  float acc[8];
  #pragma unroll
  for (int l = 0; l < 8; ++l) acc[l] = __fmul_rn(a0[l], q[l]);
  #pragma unroll
  for (int t2 = 1; t2 < 8; ++t2) {
    #pragma unroll
    for (int l = 0; l < 8; ++l)
      acc[l] = __fadd_rn(acc[l], __fmul_rn(a0[t2 * 8 + l], q[t2 * 8 + l]));
  }
  float s0 = __fadd_rn(__fadd_rn(__fadd_rn(acc[0], acc[4]), __fadd_rn(acc[2], acc[6])),
                       __fadd_rn(__fadd_rn(acc[1], acc[5]), __fadd_rn(acc[3], acc[7])));

  #pragma unroll
  for (int l = 0; l < 8; ++l) acc[l] = __fmul_rn(a1[l], q[64 + l]);
  #pragma unroll
  for (int t2 = 1; t2 < 8; ++t2) {
    #pragma unroll
    for (int l = 0; l < 8; ++l)
      acc[l] = __fadd_rn(acc[l], __fmul_rn(a1[t2 * 8 + l], q[64 + t2 * 8 + l]));
  }
  float s1 = __fadd_rn(__fadd_rn(__fadd_rn(acc[0], acc[4]), __fadd_rn(acc[2], acc[6])),
                       __fadd_rn(__fadd_rn(acc[1], acc[5]), __fadd_rn(acc[3], acc[7])));
  out[b] = __fadd_rn(s0, s1);
}

// ---------------------------------------------------------------------------
// Launch — no workspace, launches only, capture-safe.
// ---------------------------------------------------------------------------
extern "C" void kernel_launch(void* const* d_in, const int* in_sizes, int n_in,
                              void* d_out, int out_size, void* d_ws, size_t ws_size,
                              hipStream_t stream) {
  const float* query     = (const float*)d_in[0];
  const int*   pos_items = (const int*)d_in[1];
  const float* c0  = (const float*)d_in[3];
  const float* c1  = (const float*)d_in[4];
  const float* wkk = (const float*)d_in[5];
  const float* c0_ = (const float*)d_in[6];
  const float* c1_ = (const float*)d_in[7];
  const int* cd0     = (const int*)d_in[8];
  const int* cd1     = (const int*)d_in[9];
  const int* indices = (const int*)d_in[10];
  const int* indptr  = (const int*)d_in[11];

  const int B = in_sizes[0] / 128;            // 4096
  int nneg = (out_size - B) / (2 * B);        // 200
  if (nneg < 1) nneg = 1;
  const int total = B * nneg;
  const int n_items = in_sizes[10];           // 1,000,000
  const int cd_len  = in_sizes[8];            // 1,000,001

  float* out = (float*)d_out;
  float* out_pos   = out;               // [B]
  float* out_items = out + B;           // [B*nneg]
  float* out_prob  = out + B + total;   // [B*nneg]

  // split(key(42), 3), partitionable foldlike (H1): child i = TF(key,(0,i))
  uint32_t ka0, ka1, kb0, kb1, kc0, kc1;
  threefry2x32_host(0u, 42u, 0u, 0u, ka0, ka1);
  threefry2x32_host(0u, 42u, 0u, 1u, kb0, kb1);
  threefry2x32_host(0u, 42u, 0u, 2u, kc0, kc1);

  k_fused<<<B, 256, 0, stream>>>(query, c0, c1, wkk, indptr, indices,
                                 out_items, out_prob, nneg, n_items,
                                 ka0, ka1, kb0, kb1, kc0, kc1);
  k_pos<<<(B + 255) / 256, 256, 0, stream>>>(query, pos_items, cd0, cd1,
                                             c0_, c1_, out_pos, B, cd_len);
}

// Round 14
// 423.982 us; speedup vs baseline: 1.5084x; 1.0456x over previous
//
#include <hip/hip_runtime.h>
#include <stdint.h>
#include <math.h>

// ---------------------------------------------------------------------------
// ROUND 14: OCCUPANCY + ILP (baseline R13: 443us, absmax 0.0).
// R13 post-mortem: VGPR 64->68 crossed the gfx950 occupancy step (waves/SIMD
// 8->4, OccupancyPercent 42.5->33.5) — ate half the predicted win. Fixes:
//  1. __launch_bounds__(256, 8): force VGPR<=64 => 8 waves/SIMD again
//     (LDS 18.4KB x 8 blocks = 147KB <= 160KB, not limiting).
//  2. gumbel2: ONE noinline call computes gumbels for counters (m, m+1) —
//     two independent threefry+2xlogf chains in one straight-line body:
//     halves call count, 2-way ILP inside the dependency-bound chain.
//     Bit-exact: same tf_core/logf_core per counter; compares stay in
//     k-order (first-max-wins preserved). Compiled once (no compile bomb).
// Numerics stack (H1-H6, bit-exact since R12) untouched.
// ---------------------------------------------------------------------------

__device__ __host__ __forceinline__ uint32_t rotl32(uint32_t x, int d) {
  return (x << d) | (x >> (32 - d));
}

// 20-round threefry2x32 core (bit-exact per jax/_src/prng.py). Forceinline,
// but ONLY called from straight-line noinline wrappers — never from loops.
__device__ __forceinline__ void tf_core(uint32_t k0, uint32_t k1,
                                        uint32_t c0, uint32_t c1,
                                        uint32_t& o0, uint32_t& o1) {
  const uint32_t ks2 = k0 ^ k1 ^ 0x1BD11BDAu;
  uint32_t x0 = c0 + k0;
  uint32_t x1 = c1 + k1;
  x0 += x1; x1 = rotl32(x1, 13); x1 ^= x0;
  x0 += x1; x1 = rotl32(x1, 15); x1 ^= x0;
  x0 += x1; x1 = rotl32(x1, 26); x1 ^= x0;
  x0 += x1; x1 = rotl32(x1, 6);  x1 ^= x0;
  x0 += k1;  x1 += ks2 + 1u;
  x0 += x1; x1 = rotl32(x1, 17); x1 ^= x0;
  x0 += x1; x1 = rotl32(x1, 29); x1 ^= x0;
  x0 += x1; x1 = rotl32(x1, 16); x1 ^= x0;
  x0 += x1; x1 = rotl32(x1, 24); x1 ^= x0;
  x0 += ks2; x1 += k0 + 2u;
  x0 += x1; x1 = rotl32(x1, 13); x1 ^= x0;
  x0 += x1; x1 = rotl32(x1, 15); x1 ^= x0;
  x0 += x1; x1 = rotl32(x1, 26); x1 ^= x0;
  x0 += x1; x1 = rotl32(x1, 6);  x1 ^= x0;
  x0 += k0;  x1 += k1 + 3u;
  x0 += x1; x1 = rotl32(x1, 17); x1 ^= x0;
  x0 += x1; x1 = rotl32(x1, 29); x1 ^= x0;
  x0 += x1; x1 = rotl32(x1, 16); x1 ^= x0;
  x0 += x1; x1 = rotl32(x1, 24); x1 ^= x0;
  x0 += k1;  x1 += ks2 + 4u;
  x0 += x1; x1 = rotl32(x1, 13); x1 ^= x0;
  x0 += x1; x1 = rotl32(x1, 15); x1 ^= x0;
  x0 += x1; x1 = rotl32(x1, 26); x1 ^= x0;
  x0 += x1; x1 = rotl32(x1, 6);  x1 ^= x0;
  x0 += ks2; x1 += k0 + 5u;
  o0 = x0; o1 = x1;
}

// Cephes plog core (H3). Straight-line call sites only.
__device__ __forceinline__ float logf_core(float x) {
  uint32_t ix = __float_as_uint(x);
  float e = (float)((int)(ix >> 23) - 126);
  float m = __uint_as_float((ix & 0x807fffffu) | 0x3f000000u);  // [0.5, 1)
  if (m < 0.707106781186547524f) { e -= 1.0f; m = __fadd_rn(m, m); }
  m = __fsub_rn(m, 1.0f);
  float x2 = __fmul_rn(m, m);
  float x3 = __fmul_rn(x2, m);
  float y  = fmaf(7.0376836292e-2f,  m, -1.1514610310e-1f);
  float y1 = fmaf(-1.2420140846e-1f, m,  1.4249322787e-1f);
  float y2 = fmaf(2.0000714765e-1f,  m, -2.4999993993e-1f);
  y  = fmaf(y,  m,  1.1676998740e-1f);
  y1 = fmaf(y1, m, -1.6668057665e-1f);
  y2 = fmaf(y2, m,  3.3333331174e-1f);
  y = fmaf(y, x3, y1);
  y = fmaf(y, x3, y2);
  y = __fmul_rn(y, x3);
  y = fmaf(e, -2.12194440e-4f, y);
  y = __fsub_rn(y, __fmul_rn(0.5f, x2));
  float r = __fadd_rn(m, y);
  r = fmaf(e, 0.693359375f, r);
  return r;
}

// bits -> gumbel input u per jax.random.uniform(minval=tiny) semantics.
__device__ __forceinline__ float bits_to_u(uint32_t bits) {
  float f = __fsub_rn(__uint_as_float((bits >> 9) | 0x3f800000u), 1.0f);
  return (f == 0.0f) ? 1.17549435082228751e-38f : f;
}

// Noinline wrappers — what loops may call.
__device__ __attribute__((noinline)) void threefry2x32(
    uint32_t k0, uint32_t k1, uint32_t c0, uint32_t c1,
    uint32_t& o0, uint32_t& o1) {
  tf_core(k0, k1, c0, c1, o0, o1);
}

__device__ __attribute__((noinline)) float xla_logf(float x) {
  return logf_core(x);
}

// Cephes pexp (H4), inputs in [-46, 0]. Phase-1 only.
__device__ __attribute__((noinline)) float xla_expf(float x) {
  float fx = floorf(fmaf(x, 1.44269504088896341f, 0.5f));
  float r = __fsub_rn(x, __fmul_rn(fx, 0.693359375f));
  r = __fsub_rn(r, __fmul_rn(fx, -2.12194440e-4f));
  float zz = __fmul_rn(r, r);
  float y = 1.9875691500e-4f;
  y = fmaf(y, r, 1.3981999507e-3f);
  y = fmaf(y, r, 8.3334519073e-3f);
  y = fmaf(y, r, 4.1665795894e-2f);
  y = fmaf(y, r, 1.6666665459e-1f);
  y = fmaf(y, r, 5.0000001201e-1f);
  y = fmaf(y, zz, r);
  y = __fadd_rn(y, 1.0f);
  int n = (int)fx;
  float s = __uint_as_float((uint32_t)(n + 127) << 23);
  return __fmul_rn(y, s);
}

// TWO gumbels per call: counters m and m+1. Two independent chains in one
// straight-line body => 2-way ILP, half the call overhead. Bit-identical
// per-counter op sequence to the R12/R13 single gumbel.
__device__ __attribute__((noinline)) float2 gumbel2(uint32_t k0, uint32_t k1,
                                                    uint32_t m) {
  uint32_t a0, a1, b0, b1;
  tf_core(k0, k1, 0u, m,      a0, a1);
  tf_core(k0, k1, 0u, m + 1u, b0, b1);
  float uA = bits_to_u(a0 ^ a1);                                 // H2
  float uB = bits_to_u(b0 ^ b1);
  float gA = -logf_core(-logf_core(uA));
  float gB = -logf_core(-logf_core(uB));
  return make_float2(gA, gB);
}

// XLA-CPU row reduction, width 8 + tree (H6).
__device__ __forceinline__ float xla_rowsum64(const float* v) {
  float acc[8];
  #pragma unroll
  for (int l = 0; l < 8; ++l) acc[l] = v[l];
  #pragma unroll
  for (int t = 1; t < 8; ++t) {
    #pragma unroll
    for (int l = 0; l < 8; ++l) acc[l] = __fadd_rn(acc[l], v[t * 8 + l]);
  }
  float b0 = __fadd_rn(acc[0], acc[4]);
  float b1 = __fadd_rn(acc[1], acc[5]);
  float b2 = __fadd_rn(acc[2], acc[6]);
  float b3 = __fadd_rn(acc[3], acc[7]);
  return __fadd_rn(__fadd_rn(b0, b2), __fadd_rn(b1, b3));
}

__device__ __forceinline__ int clampi(int v, int lo, int hi) {
  return v < lo ? lo : (v > hi ? hi : v);
}

__device__ __forceinline__ int ld_int(const int* p32, int i, bool is64) {
  return p32[is64 ? 2 * i : i];
}

static void threefry2x32_host(uint32_t k0, uint32_t k1, uint32_t c0, uint32_t c1,
                              uint32_t& o0, uint32_t& o1) {
  const uint32_t ks2 = k0 ^ k1 ^ 0x1BD11BDAu;
  uint32_t x0 = c0 + k0;
  uint32_t x1 = c1 + k1;
  x0 += x1; x1 = rotl32(x1, 13); x1 ^= x0;
  x0 += x1; x1 = rotl32(x1, 15); x1 ^= x0;
  x0 += x1; x1 = rotl32(x1, 26); x1 ^= x0;
  x0 += x1; x1 = rotl32(x1, 6);  x1 ^= x0;
  x0 += k1;  x1 += ks2 + 1u;
  x0 += x1; x1 = rotl32(x1, 17); x1 ^= x0;
  x0 += x1; x1 = rotl32(x1, 29); x1 ^= x0;
  x0 += x1; x1 = rotl32(x1, 16); x1 ^= x0;
  x0 += x1; x1 = rotl32(x1, 24); x1 ^= x0;
  x0 += ks2; x1 += k0 + 2u;
  x0 += x1; x1 = rotl32(x1, 13); x1 ^= x0;
  x0 += x1; x1 = rotl32(x1, 15); x1 ^= x0;
  x0 += x1; x1 = rotl32(x1, 26); x1 ^= x0;
  x0 += x1; x1 = rotl32(x1, 6);  x1 ^= x0;
  x0 += k0;  x1 += k1 + 3u;
  x0 += x1; x1 = rotl32(x1, 17); x1 ^= x0;
  x0 += x1; x1 = rotl32(x1, 29); x1 ^= x0;
  x0 += x1; x1 = rotl32(x1, 16); x1 ^= x0;
  x0 += x1; x1 = rotl32(x1, 24); x1 ^= x0;
  x0 += k1;  x1 += ks2 + 4u;
  x0 += x1; x1 = rotl32(x1, 13); x1 ^= x0;
  x0 += x1; x1 = rotl32(x1, 15); x1 ^= x0;
  x0 += x1; x1 = rotl32(x1, 26); x1 ^= x0;
  x0 += x1; x1 = rotl32(x1, 6);  x1 ^= x0;
  x0 += ks2; x1 += k0 + 5u;
  o0 = x0; o1 = x1;
}

// ---------------------------------------------------------------------------
// Fused kernel. __launch_bounds__(256, 8): 8 waves/EU => VGPR capped at 64
// (R12 fit 64 naturally; R13's 68 halved occupancy — that was the regression).
// ---------------------------------------------------------------------------
__global__ void __launch_bounds__(256, 8) k_fused(
    const float* __restrict__ query, const float* __restrict__ c0g,
    const float* __restrict__ c1g, const float* __restrict__ wkk,
    const int* __restrict__ indptr, const int* __restrict__ indices,
    float* __restrict__ out_items, float* __restrict__ out_prob,
    int nneg, int n_items,
    uint32_t ka0, uint32_t ka1, uint32_t kb0, uint32_t kb1,
    uint32_t kc0, uint32_t kc1) {
  const int b = blockIdx.x;
  const int t = threadIdx.x;
  const bool is64 = (indptr[1] == 0);   // int64-materialization detection

  __shared__ float sq0[64], sq1[64], sa[64];
  __shared__ float sr0[64], sr1[64], sr1s[64], sl0[64];
  __shared__ float lw[64 * 65];         // stride 65: bank-spread

  if (t < 64) {
    sq0[t] = query[b * 128 + t];
    sq1[t] = query[b * 128 + 64 + t];
  }
  __syncthreads();

  float acc0 = 0.0f, acc1 = 0.0f;
  if (t < 64) {
    const float* c0r = c0g + t * 64;
    const float* c1r = c1g + t * 64;
    for (int k = 0; k < 64; ++k) {
      acc0 = fmaf(sq0[k], c0r[k], acc0);   // Eigen gebp serial-k (H5)
      acc1 = fmaf(sq1[k], c1r[k], acc1);
    }
    sr0[t] = acc0;
    sr1[t] = acc1;
    sa[t] = acc0;
  }
  __syncthreads();

  float e0 = 0.0f;
  if (t < 64) {
    float mx = sa[0];
    for (int k = 1; k < 64; ++k) mx = fmaxf(mx, sa[k]);
    e0 = xla_expf(__fsub_rn(acc0, mx));
  }
  __syncthreads();
  if (t < 64) sa[t] = e0;
  __syncthreads();

  float r0s = 0.0f;
  if (t < 64) {
    float s = xla_rowsum64(sa);
    r0s = e0 / s;
  }
  __syncthreads();
  if (t < 64) sa[t] = acc1;
  __syncthreads();

  float e1 = 0.0f;
  if (t < 64) {
    float mx = sa[0];
    for (int k = 1; k < 64; ++k) mx = fmaxf(mx, sa[k]);
    e1 = xla_expf(__fsub_rn(acc1, mx));
  }
  __syncthreads();
  if (t < 64) sa[t] = e1;
  __syncthreads();

  if (t < 64) {
    float s1 = xla_rowsum64(sa);
    sr1s[t] = e1 / s1;
  }
  __syncthreads();

  // lw table: 4096 entries, 16 per thread, amortized over nneg samples.
  for (int i = t; i < 4096; i += 256) {
    int kk = i >> 6, k = i & 63;
    lw[kk * 65 + k] = xla_logf(__fmul_rn(wkk[i], sr1s[k]));
  }
  if (t < 64) {
    float d = 0.0f;
    const float* wr = wkk + t * 64;
    for (int k = 0; k < 64; ++k) d = fmaf(sr1s[k], wr[k], d);
    sl0[t] = xla_logf(__fmul_rn(d, r0s));
  }
  __syncthreads();

  for (int j = t; j < nneg; j += blockDim.x) {
    int tid = b * nneg + j;
    uint32_t mbase = (uint32_t)tid * 64u;

    // k0 = argmax_k gumbel_a + log(s0); first-max-wins, compares in k-order
    float best = -INFINITY; int k0 = 0;
    #pragma unroll 1
    for (int k = 0; k < 64; k += 2) {
      float2 g = gumbel2(ka0, ka1, mbase + (uint32_t)k);
      float v0 = __fadd_rn(g.x, sl0[k]);
      if (v0 > best) { best = v0; k0 = k; }
      float v1 = __fadd_rn(g.y, sl0[k + 1]);
      if (v1 > best) { best = v1; k0 = k + 1; }
    }

    // k1 = argmax_k gumbel_b + lw[k0][k]
    const float* lwr = lw + k0 * 65;
    float best1 = -INFINITY; int k1 = 0;
    #pragma unroll 1
    for (int k = 0; k < 64; k += 2) {
      float2 g = gumbel2(kb0, kb1, mbase + (uint32_t)k);
      float v0 = __fadd_rn(g.x, lwr[k]);
      if (v0 > best1) { best1 = v0; k1 = k; }
      float v1 = __fadd_rn(g.y, lwr[k + 1]);
      if (v1 > best1) { best1 = v1; k1 = k + 1; }
    }

    float p01 = __fadd_rn(sr0[k0], sr1[k1]);

    // uniform within bucket (key kc)
    uint32_t o0, o1;
    threefry2x32(kc0, kc1, 0u, (uint32_t)tid, o0, o1);
    uint32_t bits = o0 ^ o1;                                    // H2
    float u = __fsub_rn(__uint_as_float((bits >> 9) | 0x3f800000u), 1.0f);

    int k01 = clampi(k0 * 64 + k1, 0, 4095);
    int st  = ld_int(indptr, k01, is64);
    int en  = ld_int(indptr, k01 + 1, is64);
    int cnt = en - st;
    int idx = (int)floorf(__fmul_rn((float)cnt, u));
    int cap = cnt - 1; if (cap < 0) cap = 0;
    if (idx > cap) idx = cap;
    if (idx < 0) idx = 0;
    int gidx = clampi(st + idx, 0, n_items - 1);      // fault-proof gather
    out_items[tid] = (float)(ld_int(indices, gidx, is64) + 1);  // exact in f32
    out_prob[tid] = p01;
  }
}

// ---------------------------------------------------------------------------
// pos_prop[b] = sum(c0_[cd0[pos]] * q0) + sum(c1_[cd1[pos]] * q1)
// ---------------------------------------------------------------------------
__global__ void __launch_bounds__(256) k_pos(
    const float* __restrict__ query, const int* __restrict__ pos_items,
    const int* __restrict__ cd0, const int* __restrict__ cd1,
    const float* __restrict__ c0_, const float* __restrict__ c1_,
    float* __restrict__ out, int B, int cd_len) {
  int b = blockIdx.x * blockDim.x + threadIdx.x;
  if (b >= B) return;
  const bool is64p = (pos_items[1] == 0);
  const bool is64c = (cd0[1] == 0);
  int it = clampi(ld_int(pos_items, b, is64p), 0, cd_len - 1);
  int kp0 = clampi(ld_int(cd0, it, is64c), 0, 64);
  int kp1 = clampi(ld_int(cd1, it, is64c), 0, 64);
  const float* q = query + b * 128;
  const float* a0 = c0_ + kp0 * 64;
  const float* a1 = c1_ + kp1 * 64;

  float acc[8];
  #pragma unroll
  for (int l = 0; l < 8; ++l) acc[l] = __fmul_rn(a0[l], q[l]);
  #pragma unroll
  for (int t2 = 1; t2 < 8; ++t2) {
    #pragma unroll
    for (int l = 0; l < 8; ++l)
      acc[l] = __fadd_rn(acc[l], __fmul_rn(a0[t2 * 8 + l], q[t2 * 8 + l]));
  }
  float s0 = __fadd_rn(__fadd_rn(__fadd_rn(acc[0], acc[4]), __fadd_rn(acc[2], acc[6])),
                       __fadd_rn(__fadd_rn(acc[1], acc[5]), __fadd_rn(acc[3], acc[7])));

  #pragma unroll
  for (int l = 0; l < 8; ++l) acc[l] = __fmul_rn(a1[l], q[64 + l]);
  #pragma unroll
  for (int t2 = 1; t2 < 8; ++t2) {
    #pragma unroll
    for (int l = 0; l < 8; ++l)
      acc[l] = __fadd_rn(acc[l], __fmul_rn(a1[t2 * 8 + l], q[64 + t2 * 8 + l]));
  }
  float s1 = __fadd_rn(__fadd_rn(__fadd_rn(acc[0], acc[4]), __fadd_rn(acc[2], acc[6])),
                       __fadd_rn(__fadd_rn(acc[1], acc[5]), __fadd_rn(acc[3], acc[7])));
  out[b] = __fadd_rn(s0, s1);
}

// ---------------------------------------------------------------------------
// Launch — no workspace, launches only, capture-safe.
// ---------------------------------------------------------------------------
extern "C" void kernel_launch(void* const* d_in, const int* in_sizes, int n_in,
                              void* d_out, int out_size, void* d_ws, size_t ws_size,
                              hipStream_t stream) {
  const float* query     = (const float*)d_in[0];
  const int*   pos_items = (const int*)d_in[1];
  const float* c0  = (const float*)d_in[3];
  const float* c1  = (const float*)d_in[4];
  const float* wkk = (const float*)d_in[5];
  const float* c0_ = (const float*)d_in[6];
  const float* c1_ = (const float*)d_in[7];
  const int* cd0     = (const int*)d_in[8];
  const int* cd1     = (const int*)d_in[9];
  const int* indices = (const int*)d_in[10];
  const int* indptr  = (const int*)d_in[11];

  const int B = in_sizes[0] / 128;            // 4096
  int nneg = (out_size - B) / (2 * B);        // 200
  if (nneg < 1) nneg = 1;
  const int total = B * nneg;
  const int n_items = in_sizes[10];           // 1,000,000
  const int cd_len  = in_sizes[8];            // 1,000,001

  float* out = (float*)d_out;
  float* out_pos   = out;               // [B]
  float* out_items = out + B;           // [B*nneg]
  float* out_prob  = out + B + total;   // [B*nneg]

  // split(key(42), 3), partitionable foldlike (H1): child i = TF(key,(0,i))
  uint32_t ka0, ka1, kb0, kb1, kc0, kc1;
  threefry2x32_host(0u, 42u, 0u, 0u, ka0, ka1);
  threefry2x32_host(0u, 42u, 0u, 1u, kb0, kb1);
  threefry2x32_host(0u, 42u, 0u, 2u, kc0, kc1);

  k_fused<<<B, 256, 0, stream>>>(query, c0, c1, wkk, indptr, indices,
                                 out_items, out_prob, nneg, n_items,
                                 ka0, ka1, kb0, kb1, kc0, kc1);
  k_pos<<<(B + 255) / 256, 256, 0, stream>>>(query, pos_items, cd0, cd1,
                                             c0_, c1_, out_pos, B, cd_len);
}